// Round 2
// baseline (306.218 us; speedup 1.0000x reference)
//
#include <hip/hip_runtime.h>
#include <math.h>

// CapsuleLayer fused kernel: u = x@W (fp32 GEMM, vector ALU), then 3 dynamic
// routing iterations entirely in registers/wave-shuffles, write v only.
//
// x: [32768, 512] fp32   W: [512, 512] fp32 (16 caps x 32 dims)
// out v: [32768, 32] fp32
//
// Layout: block = 512 threads (8 waves), BM=64 rows, BN=512 (full), BK=16.
// Wave w owns rows w*8..w*8+7 completely; lane l holds cols 8l..8l+7 which
// lie in one capsule (cap = l>>2), dim-group (l&3)*8..+7. All routing
// reductions are intra-wave xor-shuffle butterflies.

#define BATCH    32768
#define IN_DIM   512
#define NCOLS    512      // NUM_CAPSULES * OUT_DIM
#define OUT_DIM  32
#define BM       64
#define BK       16
#define EPS_F    1e-8f

__device__ __forceinline__ void ld_g2l_16(void* lds, const void* g) {
    // async global->LDS, 16B per lane; LDS dst = uniform base + lane*16
    __builtin_amdgcn_global_load_lds(
        (const __attribute__((address_space(1))) void*)g,
        (__attribute__((address_space(3))) void*)lds, 16, 0, 0);
}

__global__ __launch_bounds__(512, 4)
void capsule_fused(const float* __restrict__ x, const float* __restrict__ W,
                   float* __restrict__ out) {
    __shared__ float As[BK][BM + 4];   // transposed A tile, stride 68 floats
    __shared__ float Bs[BK][NCOLS];    // W tile, 32 KB

    const int tid  = threadIdx.x;
    const int w    = tid >> 6;         // wave 0..7
    const int lane = tid & 63;
    const int rowBase = blockIdx.x * BM;

    float acc[8][8];
#pragma unroll
    for (int i = 0; i < 8; ++i)
#pragma unroll
        for (int j = 0; j < 8; ++j) acc[i][j] = 0.f;

    // A staging: thread reads float2 of its row, writes transposed to LDS
    const int arow = tid >> 3;          // 0..63
    const int aj   = (tid & 7) * 2;     // 0,2,...,14
    const float* xrow = x + (size_t)(rowBase + arow) * IN_DIM + aj;

    // B staging: wave w owns k-rows 2w, 2w+1 of the tile
    const int bk0 = 2 * w;

    for (int kt = 0; kt < IN_DIM / BK; ++kt) {
        __syncthreads();               // previous tile fully consumed
        const float2 a2 = *(const float2*)(xrow + kt * BK);
        As[aj][arow]     = a2.x;
        As[aj + 1][arow] = a2.y;
        const float* wb = W + (size_t)(kt * BK + bk0) * NCOLS;
        ld_g2l_16(&Bs[bk0][0],       wb + lane * 4);
        ld_g2l_16(&Bs[bk0][256],     wb + 256 + lane * 4);
        ld_g2l_16(&Bs[bk0 + 1][0],   wb + NCOLS + lane * 4);
        ld_g2l_16(&Bs[bk0 + 1][256], wb + NCOLS + 256 + lane * 4);
        __syncthreads();               // drains vmcnt+lgkmcnt before barrier

#pragma unroll
        for (int k = 0; k < BK; ++k) {
            const float4 a0 = *(const float4*)&As[k][w * 8];       // broadcast
            const float4 a1 = *(const float4*)&As[k][w * 8 + 4];
            const float4 b0 = *(const float4*)&Bs[k][lane * 8];
            const float4 b1 = *(const float4*)&Bs[k][lane * 8 + 4];
            const float av[8] = {a0.x, a0.y, a0.z, a0.w, a1.x, a1.y, a1.z, a1.w};
            const float bv[8] = {b0.x, b0.y, b0.z, b0.w, b1.x, b1.y, b1.z, b1.w};
#pragma unroll
            for (int i = 0; i < 8; ++i)
#pragma unroll
                for (int j = 0; j < 8; ++j)
                    acc[i][j] = fmaf(av[i], bv[j], acc[i][j]);
        }
    }

    // ---- dynamic routing, per row, intra-wave ----
    const int dgrp = lane & 3;         // dims dgrp*8 .. dgrp*8+7
#pragma unroll
    for (int ri = 0; ri < 8; ++ri) {
        float b_own = 0.f;
        float v[8];
#pragma unroll
        for (int it = 0; it < 3; ++it) {
            float c_own;
            if (it == 0) {
                c_own = 1.0f / 16.0f;  // softmax of zeros
            } else {
                float m = b_own;
#pragma unroll
                for (int mask = 4; mask <= 32; mask <<= 1)
                    m = fmaxf(m, __shfl_xor(m, mask));
                const float e = __expf(b_own - m);
                float ssum = e;
#pragma unroll
                for (int mask = 4; mask <= 32; mask <<= 1)
                    ssum += __shfl_xor(ssum, mask);
                c_own = e / ssum;
            }
            // s[d] = sum_caps c_j * u[j][d]  (butterfly over capsule lanes)
            float s[8];
#pragma unroll
            for (int j = 0; j < 8; ++j) s[j] = c_own * acc[ri][j];
#pragma unroll
            for (int mask = 4; mask <= 32; mask <<= 1) {
#pragma unroll
                for (int j = 0; j < 8; ++j) s[j] += __shfl_xor(s[j], mask);
            }
            // squash
            float nrm = 0.f;
#pragma unroll
            for (int j = 0; j < 8; ++j) nrm = fmaf(s[j], s[j], nrm);
            nrm += __shfl_xor(nrm, 1);
            nrm += __shfl_xor(nrm, 2);
            const float scale = nrm / ((1.f + nrm) * (sqrtf(nrm) + EPS_F));
#pragma unroll
            for (int j = 0; j < 8; ++j) v[j] = scale * s[j];
            if (it < 2) {
                // b += u . v  (reduce over this capsule's 4 dim-group lanes)
                float dot = 0.f;
#pragma unroll
                for (int j = 0; j < 8; ++j) dot = fmaf(acc[ri][j], v[j], dot);
                dot += __shfl_xor(dot, 1);
                dot += __shfl_xor(dot, 2);
                b_own += dot;
            }
        }
        if (lane < 4) {                // one replica per dim-group writes
            float4* o = (float4*)(out + (size_t)(rowBase + w * 8 + ri) * OUT_DIM
                                  + dgrp * 8);
            o[0] = make_float4(v[0], v[1], v[2], v[3]);
            o[1] = make_float4(v[4], v[5], v[6], v[7]);
        }
    }
}

extern "C" void kernel_launch(void* const* d_in, const int* in_sizes, int n_in,
                              void* d_out, int out_size, void* d_ws, size_t ws_size,
                              hipStream_t stream) {
    const float* x = (const float*)d_in[0];   // [32768, 512]
    const float* W = (const float*)d_in[1];   // [512, 512]
    float* out = (float*)d_out;               // [32768, 32]
    dim3 grid(BATCH / BM);                    // 512 blocks
    dim3 block(512);                          // 8 waves
    capsule_fused<<<grid, block, 0, stream>>>(x, W, out);
}

// Round 3
// 269.854 us; speedup vs baseline: 1.1348x; 1.1348x over previous
//
#include <hip/hip_runtime.h>
#include <math.h>

// CapsuleLayer: u = x@W via split-precision f16 MFMA (xh@Wh + xh@Wl + xl@Wh),
// then 3 dynamic-routing iterations with the proven intra-wave butterfly code.
//
// x: [32768, 512] fp32   W: [512, 512] fp32   out v: [32768, 32] fp32
// prep_w: W[k][n] fp32 -> WhT[n][k], WlT[n][k] f16 (transposed split) in d_ws.
//
// Main kernel: block = 512 thr (8 waves), tile 64 rows x 512 cols.
// Wave (r = w>>2, c = w&3): rows R0 = blk*64 + 32r .. +31, cols 128c .. +127.
// 16x16x32 f16 MFMA, wave tile = 2 m-tiles x 8 n-tiles, 64 acc VGPRs.
// No LDS / no barriers in the K-loop: A frags straight from x (L2),
// B frags straight from WhT/WlT (L2-resident, 1 MB total).
// Epilogue: acc -> u_lds fp32 in two 32-row phases, then register routing.

#define BATCH   32768
#define KDIM    512
#define NDIM    512
#define OUT_DIM 32
#define EPS_F   1e-8f

typedef _Float16 half8 __attribute__((ext_vector_type(8)));
typedef float  floatx4 __attribute__((ext_vector_type(4)));

// ---- prep: W[k][n] fp32 -> WhT[n][k] + WlT[n][k] f16 hi/lo split ----
__global__ void prep_w(const float* __restrict__ W, _Float16* __restrict__ WhT,
                       _Float16* __restrict__ WlT) {
    __shared__ float tile[32][33];
    const int tx = threadIdx.x, ty = threadIdx.y;      // block (32, 8)
    const int n0 = blockIdx.x * 32, k0 = blockIdx.y * 32;
#pragma unroll
    for (int i = 0; i < 4; ++i)
        tile[ty + 8 * i][tx] = W[(size_t)(k0 + ty + 8 * i) * NDIM + n0 + tx];
    __syncthreads();
#pragma unroll
    for (int i = 0; i < 4; ++i) {
        const float v = tile[tx][ty + 8 * i];          // = W[k0+tx][n0+ty+8i]
        const _Float16 h = (_Float16)v;
        const _Float16 l = (_Float16)(v - (float)h);
        WhT[(size_t)(n0 + ty + 8 * i) * KDIM + k0 + tx] = h;
        WlT[(size_t)(n0 + ty + 8 * i) * KDIM + k0 + tx] = l;
    }
}

__global__ __launch_bounds__(512, 4)
void capsule_mfma(const float* __restrict__ x, const _Float16* __restrict__ WhT,
                  const _Float16* __restrict__ WlT, float* __restrict__ out) {
    __shared__ float u_lds[32][520];   // 66.56 KB, one 32-row phase of u

    const int tid  = threadIdx.x;
    const int w    = tid >> 6;         // wave 0..7
    const int lane = tid & 63;
    const int r = w >> 2, c = w & 3;   // row-group / col-group
    const int q = lane >> 4, ln = lane & 15;
    const int rowBlk = blockIdx.x * 64;
    const int R0 = rowBlk + r * 32;
    const int C0 = c * 128;

    floatx4 acc[2][8];
#pragma unroll
    for (int mt = 0; mt < 2; ++mt)
#pragma unroll
        for (int nt = 0; nt < 8; ++nt) acc[mt][nt] = (floatx4){0.f, 0.f, 0.f, 0.f};

    // lane base pointers (frag element j=0); k offset = kt*32 added per step
    const float*    abase = x   + (size_t)(R0 + ln) * KDIM + q * 8;
    const _Float16* hbase = WhT + (size_t)(C0 + ln) * KDIM + q * 8;
    const _Float16* lbase = WlT + (size_t)(C0 + ln) * KDIM + q * 8;

#pragma unroll 1
    for (int kt = 0; kt < KDIM / 32; ++kt) {
        const int k0 = kt * 32;
        half8 ah[2], al[2];
#pragma unroll
        for (int mt = 0; mt < 2; ++mt) {
            const float* ap = abase + (size_t)mt * 16 * KDIM + k0;
            const floatx4 x0 = *(const floatx4*)ap;
            const floatx4 x1 = *(const floatx4*)(ap + 4);
            const float xv[8] = {x0[0], x0[1], x0[2], x0[3],
                                 x1[0], x1[1], x1[2], x1[3]};
#pragma unroll
            for (int j = 0; j < 8; ++j) {
                const _Float16 h = (_Float16)xv[j];
                ah[mt][j] = h;
                al[mt][j] = (_Float16)(xv[j] - (float)h);
            }
        }
#pragma unroll
        for (int nt = 0; nt < 8; ++nt) {
            const half8 bh = *(const half8*)(hbase + (size_t)nt * 16 * KDIM + k0);
            const half8 bl = *(const half8*)(lbase + (size_t)nt * 16 * KDIM + k0);
#pragma unroll
            for (int mt = 0; mt < 2; ++mt) {
                acc[mt][nt] = __builtin_amdgcn_mfma_f32_16x16x32_f16(ah[mt], bh, acc[mt][nt], 0, 0, 0);
                acc[mt][nt] = __builtin_amdgcn_mfma_f32_16x16x32_f16(ah[mt], bl, acc[mt][nt], 0, 0, 0);
                acc[mt][nt] = __builtin_amdgcn_mfma_f32_16x16x32_f16(al[mt], bh, acc[mt][nt], 0, 0, 0);
            }
        }
    }

    // ---- epilogue: two 32-row phases; u -> LDS fp32, then proven routing ----
    const int dgrp = lane & 3;         // dims dgrp*8 .. dgrp*8+7
    for (int p = 0; p < 2; ++p) {
        if (p) __syncthreads();        // phase-0 reads done before overwrite
        if (r == p) {
#pragma unroll
            for (int mt = 0; mt < 2; ++mt)
#pragma unroll
                for (int nt = 0; nt < 8; ++nt)
#pragma unroll
                    for (int reg = 0; reg < 4; ++reg)
                        u_lds[mt * 16 + q * 4 + reg][C0 + nt * 16 + ln] = acc[mt][nt][reg];
        }
        __syncthreads();
#pragma unroll 1
        for (int ri = 0; ri < 4; ++ri) {
            const int rl = w * 4 + ri;               // local row 0..31
            const floatx4 ua = *(const floatx4*)&u_lds[rl][lane * 8];
            const floatx4 ub = *(const floatx4*)&u_lds[rl][lane * 8 + 4];
            const float u8[8] = {ua[0], ua[1], ua[2], ua[3],
                                 ub[0], ub[1], ub[2], ub[3]};
            float b_own = 0.f;
            float v[8];
#pragma unroll
            for (int it = 0; it < 3; ++it) {
                float c_own;
                if (it == 0) {
                    c_own = 1.0f / 16.0f;            // softmax of zeros
                } else {
                    float m = b_own;
#pragma unroll
                    for (int mask = 4; mask <= 32; mask <<= 1)
                        m = fmaxf(m, __shfl_xor(m, mask));
                    const float e = __expf(b_own - m);
                    float ssum = e;
#pragma unroll
                    for (int mask = 4; mask <= 32; mask <<= 1)
                        ssum += __shfl_xor(ssum, mask);
                    c_own = e / ssum;
                }
                float s[8];
#pragma unroll
                for (int j = 0; j < 8; ++j) s[j] = c_own * u8[j];
#pragma unroll
                for (int mask = 4; mask <= 32; mask <<= 1) {
#pragma unroll
                    for (int j = 0; j < 8; ++j) s[j] += __shfl_xor(s[j], mask);
                }
                float nrm = 0.f;
#pragma unroll
                for (int j = 0; j < 8; ++j) nrm = fmaf(s[j], s[j], nrm);
                nrm += __shfl_xor(nrm, 1);
                nrm += __shfl_xor(nrm, 2);
                const float scale = nrm / ((1.f + nrm) * (sqrtf(nrm) + EPS_F));
#pragma unroll
                for (int j = 0; j < 8; ++j) v[j] = scale * s[j];
                if (it < 2) {
                    float dot = 0.f;
#pragma unroll
                    for (int j = 0; j < 8; ++j) dot = fmaf(u8[j], v[j], dot);
                    dot += __shfl_xor(dot, 1);
                    dot += __shfl_xor(dot, 2);
                    b_own += dot;
                }
            }
            if (lane < 4) {
                float4* o = (float4*)(out + (size_t)(rowBlk + p * 32 + rl) * OUT_DIM
                                      + dgrp * 8);
                o[0] = make_float4(v[0], v[1], v[2], v[3]);
                o[1] = make_float4(v[4], v[5], v[6], v[7]);
            }
        }
    }
}

extern "C" void kernel_launch(void* const* d_in, const int* in_sizes, int n_in,
                              void* d_out, int out_size, void* d_ws, size_t ws_size,
                              hipStream_t stream) {
    const float* x = (const float*)d_in[0];   // [32768, 512]
    const float* W = (const float*)d_in[1];   // [512, 512]
    float* out = (float*)d_out;               // [32768, 32]
    _Float16* WhT = (_Float16*)d_ws;          // [512, 512] f16
    _Float16* WlT = WhT + (size_t)NDIM * KDIM;

    prep_w<<<dim3(16, 16), dim3(32, 8), 0, stream>>>(W, WhT, WlT);
    capsule_mfma<<<dim3(BATCH / 64), dim3(512), 0, stream>>>(x, WhT, WlT, out);
}

// Round 4
// 182.999 us; speedup vs baseline: 1.6733x; 1.4746x over previous
//
#include <hip/hip_runtime.h>
#include <math.h>

// CapsuleLayer: u = x@W via split-precision f16 MFMA (xh@Wh + xl@Wh + xh@Wl),
// 32x32x16 shape, LDS double-buffered B staging (m97 pattern), A prefetched
// in registers; then 3 dynamic-routing iterations (proven butterfly code).
//
// x: [32768,512] fp32   W: [512,512] fp32   v: [32768,32] fp32
// prep_w: W[k][n] -> Wt_h/Wt_l tiled [kt][n][k%16] f16 in d_ws (1 MB).
//
// Main: block = 512 thr (8 waves), 64 rows x 512 cols. Wave (r=w>>2,c=w&3):
// rows R0 = blk*64 + 32r, cols C0 = 128c, 4 n-tiles of 32, acc = 4x16 fp32.
// Per kt (BK=16): 1 barrier; stage(kt+1) via global_load_lds (4x1KB/wave,
// contiguous); A frag prefetched one kt ahead; 8 ds_read_b128 + 12 MFMA.
// LDS: Bs[2][2][512][16] f16 (64 KB) unioned with epilogue u_lds[32][520]
// (66.56 KB) -> 2 blocks/CU.

#define BATCH   32768
#define KDIM    512
#define NDIM    512
#define OUT_DIM 32
#define EPS_F   1e-8f
#define NKT     32            // K tiles of 16

typedef _Float16 half8  __attribute__((ext_vector_type(8)));
typedef float   floatx4 __attribute__((ext_vector_type(4)));
typedef float  floatx16 __attribute__((ext_vector_type(16)));

// ---- prep: W[k][n] fp32 -> Wt_h/Wt_l [kt][n][k%16] f16 hi/lo split ----
__global__ void prep_w(const float* __restrict__ W, _Float16* __restrict__ Wh,
                       _Float16* __restrict__ Wl) {
    __shared__ float tile[32][33];
    const int tx = threadIdx.x, ty = threadIdx.y;      // block (32, 8)
    const int n0 = blockIdx.x * 32, k0 = blockIdx.y * 32;
#pragma unroll
    for (int i = 0; i < 4; ++i)
        tile[ty + 8 * i][tx] = W[(size_t)(k0 + ty + 8 * i) * NDIM + n0 + tx];
    __syncthreads();
#pragma unroll
    for (int i = 0; i < 4; ++i) {
        const int k = k0 + tx, n = n0 + ty + 8 * i;
        const float v = tile[tx][ty + 8 * i];          // = W[k][n]
        const _Float16 h = (_Float16)v;
        const _Float16 l = (_Float16)(v - (float)h);
        const size_t off = (size_t)(k >> 4) * (NDIM * 16) + (size_t)n * 16 + (k & 15);
        Wh[off] = h;
        Wl[off] = l;
    }
}

__device__ __forceinline__ void ld_g2l_16(void* lds_base_uniform, const void* g) {
    // async global->LDS; HW writes lane i at lds_base + i*16
    __builtin_amdgcn_global_load_lds(
        (const __attribute__((address_space(1))) void*)g,
        (__attribute__((address_space(3))) void*)lds_base_uniform, 16, 0, 0);
}

__global__ __launch_bounds__(512, 4)
void capsule_mfma(const float* __restrict__ x, const _Float16* __restrict__ Wh,
                  const _Float16* __restrict__ Wl, float* __restrict__ out) {
    __shared__ __align__(16) char smem[66560];         // max(Bs 64K, u_lds 66.56K)
    _Float16 (*Bs)[2][NDIM][16] = (_Float16 (*)[2][NDIM][16])smem;  // [buf][h/l][n][k']
    float (*u_lds)[520] = (float (*)[520])smem;

    const int tid  = threadIdx.x;
    const int w    = tid >> 6;          // wave 0..7
    const int lane = tid & 63;
    const int r = w >> 2, c = w & 3;    // row-group / col-group
    const int ln = lane & 31, q = lane >> 5;
    const int rowBlk = blockIdx.x * 64;
    const int R0 = rowBlk + r * 32;
    const int C0 = c * 128;

    floatx16 acc[4];
#pragma unroll
    for (int nt = 0; nt < 4; ++nt)
#pragma unroll
        for (int i = 0; i < 16; ++i) acc[nt][i] = 0.f;

    // A frag: row = ln, k = q*8 + j (32x32x16 layout), fp32 source, cvt on use
    const float* aptr = x + (size_t)(R0 + ln) * KDIM + q * 8;

    // B staging: wave w copies n in [w*64, w*64+64) for h and l (4 x 1KB instrs)
    const int nseg = w * 64;

    // ---- stage kt=0, prefetch A(0) ----
    {
        const size_t g0 = 0;
        ld_g2l_16(&Bs[0][0][nseg][0],      Wh + g0 + (size_t)nseg * 16 + lane * 8);
        ld_g2l_16(&Bs[0][0][nseg + 32][0], Wh + g0 + (size_t)(nseg + 32) * 16 + lane * 8);
        ld_g2l_16(&Bs[0][1][nseg][0],      Wl + g0 + (size_t)nseg * 16 + lane * 8);
        ld_g2l_16(&Bs[0][1][nseg + 32][0], Wl + g0 + (size_t)(nseg + 32) * 16 + lane * 8);
    }
    floatx4 a0 = *(const floatx4*)(aptr);
    floatx4 a1 = *(const floatx4*)(aptr + 4);

#pragma unroll 2
    for (int kt = 0; kt < NKT; ++kt) {
        __syncthreads();               // stage(kt) complete; buf^1 readers done
        const int buf = kt & 1;
        if (kt + 1 < NKT) {            // stage(kt+1) into other buffer (async)
            const size_t g = (size_t)(kt + 1) * (NDIM * 16);
            ld_g2l_16(&Bs[buf ^ 1][0][nseg][0],      Wh + g + (size_t)nseg * 16 + lane * 8);
            ld_g2l_16(&Bs[buf ^ 1][0][nseg + 32][0], Wh + g + (size_t)(nseg + 32) * 16 + lane * 8);
            ld_g2l_16(&Bs[buf ^ 1][1][nseg][0],      Wl + g + (size_t)nseg * 16 + lane * 8);
            ld_g2l_16(&Bs[buf ^ 1][1][nseg + 32][0], Wl + g + (size_t)(nseg + 32) * 16 + lane * 8);
        }
        floatx4 p0, p1;                // A prefetch for kt+1
        if (kt + 1 < NKT) {
            p0 = *(const floatx4*)(aptr + (kt + 1) * 16);
            p1 = *(const floatx4*)(aptr + (kt + 1) * 16 + 4);
        }
        // convert A(kt) to f16 hi/lo frags
        const float av[8] = {a0[0], a0[1], a0[2], a0[3], a1[0], a1[1], a1[2], a1[3]};
        half8 ah, al;
#pragma unroll
        for (int j = 0; j < 8; ++j) {
            const _Float16 h = (_Float16)av[j];
            ah[j] = h;
            al[j] = (_Float16)(av[j] - (float)h);
        }
#pragma unroll
        for (int nt = 0; nt < 4; ++nt) {
            const half8 bh = *(const half8*)&Bs[buf][0][C0 + nt * 32 + ln][q * 8];
            const half8 bl = *(const half8*)&Bs[buf][1][C0 + nt * 32 + ln][q * 8];
            acc[nt] = __builtin_amdgcn_mfma_f32_32x32x16_f16(ah, bh, acc[nt], 0, 0, 0);
            acc[nt] = __builtin_amdgcn_mfma_f32_32x32x16_f16(al, bh, acc[nt], 0, 0, 0);
            acc[nt] = __builtin_amdgcn_mfma_f32_32x32x16_f16(ah, bl, acc[nt], 0, 0, 0);
        }
        if (kt + 1 < NKT) { a0 = p0; a1 = p1; }
    }

    // ---- epilogue: two 32-row phases; acc -> u_lds fp32, then routing ----
    // C/D layout 32x32: col = ln, row = (reg&3) + 8*(reg>>2) + 4*q
    const int dgrp = lane & 3;
    for (int p = 0; p < 2; ++p) {
        __syncthreads();               // p=0: K-loop LDS reads done; p=1: phase-0 reads done
        if (r == p) {
#pragma unroll
            for (int nt = 0; nt < 4; ++nt)
#pragma unroll
                for (int reg = 0; reg < 16; ++reg)
                    u_lds[(reg & 3) + 8 * (reg >> 2) + 4 * q][C0 + nt * 32 + ln] = acc[nt][reg];
        }
        __syncthreads();
#pragma unroll 1
        for (int ri = 0; ri < 4; ++ri) {
            const int rl = w * 4 + ri;               // local row 0..31
            const floatx4 ua = *(const floatx4*)&u_lds[rl][lane * 8];
            const floatx4 ub = *(const floatx4*)&u_lds[rl][lane * 8 + 4];
            const float u8[8] = {ua[0], ua[1], ua[2], ua[3],
                                 ub[0], ub[1], ub[2], ub[3]};
            float b_own = 0.f;
            float v[8];
#pragma unroll
            for (int it = 0; it < 3; ++it) {
                float c_own;
                if (it == 0) {
                    c_own = 1.0f / 16.0f;            // softmax of zeros
                } else {
                    float m = b_own;
#pragma unroll
                    for (int mask = 4; mask <= 32; mask <<= 1)
                        m = fmaxf(m, __shfl_xor(m, mask));
                    const float e = __expf(b_own - m);
                    float ssum = e;
#pragma unroll
                    for (int mask = 4; mask <= 32; mask <<= 1)
                        ssum += __shfl_xor(ssum, mask);
                    c_own = e / ssum;
                }
                float s[8];
#pragma unroll
                for (int j = 0; j < 8; ++j) s[j] = c_own * u8[j];
#pragma unroll
                for (int mask = 4; mask <= 32; mask <<= 1) {
#pragma unroll
                    for (int j = 0; j < 8; ++j) s[j] += __shfl_xor(s[j], mask);
                }
                float nrm = 0.f;
#pragma unroll
                for (int j = 0; j < 8; ++j) nrm = fmaf(s[j], s[j], nrm);
                nrm += __shfl_xor(nrm, 1);
                nrm += __shfl_xor(nrm, 2);
                const float scale = nrm / ((1.f + nrm) * (sqrtf(nrm) + EPS_F));
#pragma unroll
                for (int j = 0; j < 8; ++j) v[j] = scale * s[j];
                if (it < 2) {
                    float dot = 0.f;
#pragma unroll
                    for (int j = 0; j < 8; ++j) dot = fmaf(u8[j], v[j], dot);
                    dot += __shfl_xor(dot, 1);
                    dot += __shfl_xor(dot, 2);
                    b_own += dot;
                }
            }
            if (lane < 4) {
                float4* o = (float4*)(out + (size_t)(rowBlk + p * 32 + rl) * OUT_DIM
                                      + dgrp * 8);
                o[0] = make_float4(v[0], v[1], v[2], v[3]);
                o[1] = make_float4(v[4], v[5], v[6], v[7]);
            }
        }
    }
}

extern "C" void kernel_launch(void* const* d_in, const int* in_sizes, int n_in,
                              void* d_out, int out_size, void* d_ws, size_t ws_size,
                              hipStream_t stream) {
    const float* x = (const float*)d_in[0];   // [32768, 512]
    const float* W = (const float*)d_in[1];   // [512, 512]
    float* out = (float*)d_out;               // [32768, 32]
    _Float16* Wh = (_Float16*)d_ws;           // [32][512][16] f16 tiled
    _Float16* Wl = Wh + (size_t)NDIM * KDIM;

    prep_w<<<dim3(16, 16), dim3(32, 8), 0, stream>>>(W, Wh, Wl);
    capsule_mfma<<<dim3(BATCH / 64), dim3(512), 0, stream>>>(x, Wh, Wl, out);
}